// Round 8
// baseline (122.344 us; speedup 1.0000x reference)
//
#include <hip/hip_runtime.h>

#define N_NODES  50000
#define N_EDGES  1600000
#define N_FEAT   50
#define HID      20
#define OUT_DIM  10
#define N_GRAPHS 64

#define NBUCK 256            // buckets: key = (dst*335)>>16, ~195.6 nodes each
#define BCAP  8192           // padded slots/bucket (avg ~6256, +24 sigma)
#define EPB   (N_EDGES/256)  // 6250 edges per scatter block
#define YSTR  32             // y row stride (floats): 128B rows, line-aligned
#define GEMMB 977            // ceil(N_NODES*HID/1024)

__device__ __forceinline__ int bstart(int b) { return (b * 65536 + 334) / 335; }

// ================= K1: edge scatter (1 LDS atomic/edge) || layer-1 GEMM ============
// Blocks [0,256): scatter. Blocks [256, 256+GEMMB): gemm50. gcur/done pre-zeroed.

__global__ __launch_bounds__(1024) void k1_scatter_gemm(
        const int* __restrict__ dst, const int* __restrict__ srcv,
        int* __restrict__ gcur, unsigned int* __restrict__ padded,
        const float* __restrict__ x, const float* __restrict__ Wrel,
        const float* __restrict__ Wroot, const float* __restrict__ bb,
        float* __restrict__ y, float* __restrict__ acc,
        float* __restrict__ gmax, float* __restrict__ gsum, float* __restrict__ gcnt) {
    __shared__ char smem[14560];
    int t = threadIdx.x;
    if (blockIdx.x < 256) {
        unsigned short* rnk = (unsigned short*)smem;       // 12500 B
        int* cnt   = (int*)(smem + 12512);                 // 1024 B
        int* gbase = cnt + 256;                            // 1024 B
        if (blockIdx.x == 0) {                             // pool-accum init
            for (int i = t; i < N_GRAPHS * HID; i += 1024) { gmax[i] = 0.f; gsum[i] = 0.f; }
            if (t < N_GRAPHS) gcnt[t] = 0.f;
        }
        if (t < 256) cnt[t] = 0;
        __syncthreads();
        int e0 = blockIdx.x * EPB;
        // pass 1: within-block rank per bucket (1 LDS atomic per edge)
        for (int i = t; i < EPB; i += 1024) {
            unsigned int d = (unsigned int)dst[e0 + i];
            unsigned int key = (d * 335u) >> 16;
            rnk[i] = (unsigned short)atomicAdd(&cnt[key], 1);
        }
        __syncthreads();
        if (t < 256) gbase[t] = t * BCAP + atomicAdd(&gcur[t], cnt[t]);  // 256 global atomics
        __syncthreads();
        // pass 2: direct placement (no atomic); dst/src re-read is L2-hot
        for (int i = t; i < EPB; i += 1024) {
            unsigned int d = (unsigned int)dst[e0 + i];
            unsigned int s = (unsigned int)srcv[e0 + i];
            unsigned int key = (d * 335u) >> 16;
            int gp = gbase[key] + rnk[i];
            if (gp < (int)(key + 1) * BCAP) padded[gp] = (d << 16) | s;  // guard: never fires
        }
    } else {
        float* sWrel  = (float*)smem;
        float* sWroot = sWrel + N_FEAT * HID;
        for (int i = t; i < N_FEAT * HID; i += 1024) { sWrel[i] = Wrel[i]; sWroot[i] = Wroot[i]; }
        __syncthreads();
        int idx = (blockIdx.x - 256) * 1024 + t;
        if (idx < N_NODES * HID) {
            int n = idx / HID, j = idx % HID;
            const float* xr = x + n * N_FEAT;
            float a0 = 0.f, a1 = bb[j];
            #pragma unroll
            for (int k = 0; k < N_FEAT; ++k) {
                float xv = xr[k];
                a0 = fmaf(xv, sWrel[k * HID + j], a0);
                a1 = fmaf(xv, sWroot[k * HID + j], a1);
            }
            y[n * YSTR + j] = a0;
            acc[idx] = a1;
        }
    }
}

// ================= K2: rank-trick counting sort + LPT perm + gather1 + gemm2 ========

__global__ __launch_bounds__(1024) void k2_build_gather(
        const int* __restrict__ gcur, const unsigned int* __restrict__ padded,
        unsigned short* __restrict__ csr16, int* __restrict__ startg,
        int* __restrict__ cntg, unsigned short* __restrict__ permg,
        const float* __restrict__ y_in, const float* __restrict__ accp,
        const float* __restrict__ Wrel, const float* __restrict__ Wroot,
        const float* __restrict__ bb,
        float* __restrict__ y_out, float* __restrict__ acc_out) {
    __shared__ unsigned short eo[BCAP];                    // 16 KB sorted csr
    __shared__ char uni[20480];                            // rnk (16KB) then rh (20KB)
    __shared__ float sWrel[HID * HID], sWroot[HID * HID], sb[HID];
    __shared__ int cnt[256], scn[256], s_start[256], s_cnt[256];
    __shared__ unsigned short sperm[256];
    unsigned short* rnk = (unsigned short*)uni;
    float*          rh  = (float*)uni;
    int g = blockIdx.x, t = threadIdx.x;
    int base = g * BCAP;
    int m = min(gcur[g], BCAP);
    int n0 = bstart(g);
    int n1 = min(bstart(g + 1), N_NODES);
    int nvalid = n1 - n0;
    for (int i = t; i < HID * HID; i += 1024) { sWrel[i] = Wrel[i]; sWroot[i] = Wroot[i]; }
    if (t < HID) sb[t] = bb[t];
    if (t < 256) cnt[t] = 0;
    __syncthreads();
    // pass 1: rank within node (1 LDS atomic per edge)
    for (int i = t; i < m; i += 1024) {
        int local = (int)(padded[base + i] >> 16) - n0;
        rnk[i] = (unsigned short)atomicAdd(&cnt[local], 1);
    }
    __syncthreads();
    if (t < 256) { s_cnt[t] = cnt[t]; scn[t] = cnt[t]; }
    __syncthreads();
    for (int d = 1; d < 256; d <<= 1) {
        int u = 0;
        if (t < 256 && t >= d) u = scn[t - d];
        __syncthreads();
        if (t < 256) scn[t] += u;
        __syncthreads();
    }
    if (t < 256) {
        s_start[t] = scn[t] - s_cnt[t];
        if (t < nvalid) { startg[n0 + t] = base + s_start[t]; cntg[n0 + t] = s_cnt[t]; }
    }
    __syncthreads();
    // pass 2: place (no atomic)
    for (int i = t; i < m; i += 1024) {
        unsigned int e = padded[base + i];
        int local = (int)(e >> 16) - n0;
        eo[s_start[local] + rnk[i]] = (unsigned short)(e & 0xFFFFu);
    }
    __syncthreads();
    for (int i = t; i < m; i += 1024) csr16[base + i] = eo[i];   // coalesced
    // degree-descending perm (rank by comparison, no atomics)
    if (t < 256) {
        int d = s_cnt[t], rank = 0;
        for (int j2 = 0; j2 < 256; ++j2) {
            int dj = s_cnt[j2];
            rank += (dj > d) || (dj == d && j2 < t);
        }
        sperm[rank] = (unsigned short)t;
    }
    __syncthreads();
    if (t < 256) permg[g * 256 + t] = sperm[t];
    // rnk dead -> rh init
    for (int i = t; i < nvalid * HID; i += 1024) rh[i] = accp[n0 * HID + i];
    __syncthreads();
    // LPT-paired gather: group takes ranks grp (heavy) and 255-grp (light)
    int grp = t >> 3, lane = t & 7;
    if (lane < 5) {
        int q4 = lane * 4;
        #pragma unroll
        for (int rep = 0; rep < 2; ++rep) {
            int rank = rep ? 255 - grp : grp;
            int nl = sperm[rank];
            if (nl < nvalid) {
                int a = s_start[nl], e = a + s_cnt[nl];
                float4 s0 = make_float4(0.f, 0.f, 0.f, 0.f);
                float4 s1 = make_float4(0.f, 0.f, 0.f, 0.f);
                int k = a;
                for (; k + 3 < e; k += 4) {
                    int sn0 = eo[k], sn1 = eo[k + 1], sn2 = eo[k + 2], sn3 = eo[k + 3];
                    float4 v0 = *(const float4*)(y_in + sn0 * YSTR + q4);
                    float4 v1 = *(const float4*)(y_in + sn1 * YSTR + q4);
                    float4 v2 = *(const float4*)(y_in + sn2 * YSTR + q4);
                    float4 v3 = *(const float4*)(y_in + sn3 * YSTR + q4);
                    s0.x += v0.x + v2.x; s0.y += v0.y + v2.y;
                    s0.z += v0.z + v2.z; s0.w += v0.w + v2.w;
                    s1.x += v1.x + v3.x; s1.y += v1.y + v3.y;
                    s1.z += v1.z + v3.z; s1.w += v1.w + v3.w;
                }
                for (; k < e; ++k) {
                    int sn = eo[k];
                    float4 v = *(const float4*)(y_in + sn * YSTR + q4);
                    s0.x += v.x; s0.y += v.y; s0.z += v.z; s0.w += v.w;
                }
                float* rp = &rh[nl * HID + q4];
                rp[0] += s0.x + s1.x; rp[1] += s0.y + s1.y;
                rp[2] += s0.z + s1.z; rp[3] += s0.w + s1.w;
            }
        }
    }
    __syncthreads();
    // next-layer GEMM from LDS
    for (int i = t; i < nvalid * 5; i += 1024) {
        int n = i / 5, j0 = (i % 5) * 4;
        float y0 = 0.f, y1 = 0.f, y2 = 0.f, y3 = 0.f;
        float a0 = sb[j0], a1 = sb[j0 + 1], a2 = sb[j0 + 2], a3 = sb[j0 + 3];
        #pragma unroll
        for (int k = 0; k < HID; ++k) {
            float h = fmaxf(rh[n * HID + k], 0.f);
            const float* wr = sWrel  + k * HID + j0;
            const float* wo = sWroot + k * HID + j0;
            y0 = fmaf(h, wr[0], y0); y1 = fmaf(h, wr[1], y1);
            y2 = fmaf(h, wr[2], y2); y3 = fmaf(h, wr[3], y3);
            a0 = fmaf(h, wo[0], a0); a1 = fmaf(h, wo[1], a1);
            a2 = fmaf(h, wo[2], a2); a3 = fmaf(h, wo[3], a3);
        }
        *(float4*)(y_out   + (n0 + n) * YSTR + j0) = make_float4(y0, y1, y2, y3);
        *(float4*)(acc_out + (n0 + n) * HID  + j0) = make_float4(a0, a1, a2, a3);
    }
}

// ================= K3: gather (global csr16, LPT perm) + gemm3 ======================

__global__ __launch_bounds__(1024) void k3_gather_gemm(
        const int* __restrict__ startg, const int* __restrict__ cntg,
        const unsigned short* __restrict__ csr16, const unsigned short* __restrict__ permg,
        const float* __restrict__ y_in, const float* __restrict__ accp,
        const float* __restrict__ Wrel, const float* __restrict__ Wroot,
        const float* __restrict__ bb,
        float* __restrict__ y_out, float* __restrict__ acc_out) {
    __shared__ float rh[256 * HID];
    __shared__ float sWrel[HID * HID], sWroot[HID * HID], sb[HID];
    int g = blockIdx.x, t = threadIdx.x;
    int n0 = bstart(g);
    int n1 = min(bstart(g + 1), N_NODES);
    int nvalid = n1 - n0;
    for (int i = t; i < HID * HID; i += 1024) { sWrel[i] = Wrel[i]; sWroot[i] = Wroot[i]; }
    if (t < HID) sb[t] = bb[t];
    for (int i = t; i < nvalid * HID; i += 1024) rh[i] = accp[n0 * HID + i];
    __syncthreads();
    int grp = t >> 3, lane = t & 7;
    if (lane < 5) {
        int q4 = lane * 4;
        #pragma unroll
        for (int rep = 0; rep < 2; ++rep) {
            int rank = rep ? 255 - grp : grp;
            int nl = permg[g * 256 + rank];
            if (nl < nvalid) {
                int node = n0 + nl;
                int a = startg[node], e = a + cntg[node];
                float4 s0 = make_float4(0.f, 0.f, 0.f, 0.f);
                float4 s1 = make_float4(0.f, 0.f, 0.f, 0.f);
                int k = a;
                for (; k + 3 < e; k += 4) {
                    int sn0 = csr16[k], sn1 = csr16[k + 1], sn2 = csr16[k + 2], sn3 = csr16[k + 3];
                    float4 v0 = *(const float4*)(y_in + sn0 * YSTR + q4);
                    float4 v1 = *(const float4*)(y_in + sn1 * YSTR + q4);
                    float4 v2 = *(const float4*)(y_in + sn2 * YSTR + q4);
                    float4 v3 = *(const float4*)(y_in + sn3 * YSTR + q4);
                    s0.x += v0.x + v2.x; s0.y += v0.y + v2.y;
                    s0.z += v0.z + v2.z; s0.w += v0.w + v2.w;
                    s1.x += v1.x + v3.x; s1.y += v1.y + v3.y;
                    s1.z += v1.z + v3.z; s1.w += v1.w + v3.w;
                }
                for (; k < e; ++k) {
                    int sn = csr16[k];
                    float4 v = *(const float4*)(y_in + sn * YSTR + q4);
                    s0.x += v.x; s0.y += v.y; s0.z += v.z; s0.w += v.w;
                }
                float* rp = &rh[nl * HID + q4];
                rp[0] += s0.x + s1.x; rp[1] += s0.y + s1.y;
                rp[2] += s0.z + s1.z; rp[3] += s0.w + s1.w;
            }
        }
    }
    __syncthreads();
    for (int i = t; i < nvalid * 5; i += 1024) {
        int n = i / 5, j0 = (i % 5) * 4;
        float y0 = 0.f, y1 = 0.f, y2 = 0.f, y3 = 0.f;
        float a0 = sb[j0], a1 = sb[j0 + 1], a2 = sb[j0 + 2], a3 = sb[j0 + 3];
        #pragma unroll
        for (int k = 0; k < HID; ++k) {
            float h = fmaxf(rh[n * HID + k], 0.f);
            const float* wr = sWrel  + k * HID + j0;
            const float* wo = sWroot + k * HID + j0;
            y0 = fmaf(h, wr[0], y0); y1 = fmaf(h, wr[1], y1);
            y2 = fmaf(h, wr[2], y2); y3 = fmaf(h, wr[3], y3);
            a0 = fmaf(h, wo[0], a0); a1 = fmaf(h, wo[1], a1);
            a2 = fmaf(h, wo[2], a2); a3 = fmaf(h, wo[3], a3);
        }
        *(float4*)(y_out   + (n0 + n) * YSTR + j0) = make_float4(y0, y1, y2, y3);
        *(float4*)(acc_out + (n0 + n) * HID  + j0) = make_float4(a0, a1, a2, a3);
    }
}

// ================= K4: gather + pooling + last-block final linear ===================

__global__ __launch_bounds__(1024) void k4_gather_pool(
        const int* __restrict__ startg, const int* __restrict__ cntg,
        const unsigned short* __restrict__ csr16, const unsigned short* __restrict__ permg,
        const float* __restrict__ y_in, const float* __restrict__ accp,
        const int* __restrict__ batch,
        float* __restrict__ gmax, float* __restrict__ gsum, float* __restrict__ gcnt,
        int* __restrict__ done, const float* __restrict__ Wlin,
        const float* __restrict__ blin, float* __restrict__ out) {
    __shared__ float rh[256 * HID];
    __shared__ float redm[51 * HID], reds[51 * HID];
    __shared__ int sbatch[256];
    __shared__ int seglo[16], seghi[16];
    __shared__ int lastFlag;
    int g = blockIdx.x, t = threadIdx.x;
    int n0 = bstart(g);
    int n1 = min(bstart(g + 1), N_NODES);
    int nvalid = n1 - n0;
    for (int i = t; i < nvalid * HID; i += 1024) rh[i] = accp[n0 * HID + i];
    if (t < nvalid) sbatch[t] = batch[n0 + t];
    __syncthreads();
    int grp = t >> 3, lane = t & 7;
    if (lane < 5) {
        int q4 = lane * 4;
        #pragma unroll
        for (int rep = 0; rep < 2; ++rep) {
            int rank = rep ? 255 - grp : grp;
            int nl = permg[g * 256 + rank];
            if (nl < nvalid) {
                int node = n0 + nl;
                int a = startg[node], e = a + cntg[node];
                float4 s0 = make_float4(0.f, 0.f, 0.f, 0.f);
                float4 s1 = make_float4(0.f, 0.f, 0.f, 0.f);
                int k = a;
                for (; k + 3 < e; k += 4) {
                    int sn0 = csr16[k], sn1 = csr16[k + 1], sn2 = csr16[k + 2], sn3 = csr16[k + 3];
                    float4 v0 = *(const float4*)(y_in + sn0 * YSTR + q4);
                    float4 v1 = *(const float4*)(y_in + sn1 * YSTR + q4);
                    float4 v2 = *(const float4*)(y_in + sn2 * YSTR + q4);
                    float4 v3 = *(const float4*)(y_in + sn3 * YSTR + q4);
                    s0.x += v0.x + v2.x; s0.y += v0.y + v2.y;
                    s0.z += v0.z + v2.z; s0.w += v0.w + v2.w;
                    s1.x += v1.x + v3.x; s1.y += v1.y + v3.y;
                    s1.z += v1.z + v3.z; s1.w += v1.w + v3.w;
                }
                for (; k < e; ++k) {
                    int sn = csr16[k];
                    float4 v = *(const float4*)(y_in + sn * YSTR + q4);
                    s0.x += v.x; s0.y += v.y; s0.z += v.z; s0.w += v.w;
                }
                float* rp = &rh[nl * HID + q4];
                rp[0] += s0.x + s1.x; rp[1] += s0.y + s1.y;
                rp[2] += s0.z + s1.z; rp[3] += s0.w + s1.w;
            }
        }
    }
    __syncthreads();
    int g0 = sbatch[0];
    int span = sbatch[nvalid - 1] - g0 + 1;
    if (t < nvalid) {
        int bi = sbatch[t] - g0;
        if (bi < 16) {
            if (t == 0 || sbatch[t - 1] != sbatch[t]) seglo[bi] = t;
            if (t == nvalid - 1 || sbatch[t + 1] != sbatch[t]) seghi[bi] = t + 1;
        }
    }
    __syncthreads();
    if (span > 16) span = 16;
    for (int li = 0; li < span; ++li) {
        int lo = seglo[li], hi = seghi[li];
        int r = t / HID, j = t % HID;
        if (r < 51) {
            float mx = 0.f, sm = 0.f;
            for (int n = lo + r; n < hi; n += 51) {
                float v = fmaxf(rh[n * HID + j], 0.f);
                mx = fmaxf(mx, v); sm += v;
            }
            redm[r * HID + j] = mx; reds[r * HID + j] = sm;
        }
        __syncthreads();
        if (t < HID) {
            float mm = 0.f, ss = 0.f;
            #pragma unroll 17
            for (int r2 = 0; r2 < 51; ++r2) {
                mm = fmaxf(mm, redm[r2 * HID + t]);
                ss += reds[r2 * HID + t];
            }
            atomicMax((int*)&gmax[(g0 + li) * HID + t], __float_as_int(mm));
            atomicAdd(&gsum[(g0 + li) * HID + t], ss);
        }
        if (t == HID) atomicAdd(&gcnt[g0 + li], (float)(hi - lo));
        __syncthreads();
    }
    // last block computes the final linear
    if (t == 0) {
        __threadfence();
        lastFlag = (atomicAdd(done, 1) == NBUCK - 1);
    }
    __syncthreads();
    if (!lastFlag) return;
    __threadfence();
    float* sW = redm;   // reuse LDS (400 floats)
    for (int i = t; i < 2 * HID * OUT_DIM; i += 1024) sW[i] = Wlin[i];
    __syncthreads();
    if (t < N_GRAPHS * OUT_DIM) {
        int gg = t / OUT_DIM, o = t % OUT_DIM;
        float c = fmaxf(gcnt[gg], 1.0f);
        float a = blin[o];
        #pragma unroll
        for (int j = 0; j < HID; ++j) {
            a = fmaf(gmax[gg * HID + j], sW[j * OUT_DIM + o], a);
            a = fmaf(gsum[gg * HID + j] / c, sW[(HID + j) * OUT_DIM + o], a);
        }
        out[t] = a;
    }
}

extern "C" void kernel_launch(void* const* d_in, const int* in_sizes, int n_in,
                              void* d_out, int out_size, void* d_ws, size_t ws_size,
                              hipStream_t stream) {
    const float* x      = (const float*)d_in[0];
    const int*   ei     = (const int*)  d_in[1];
    const int*   batch  = (const int*)  d_in[2];
    const float* Wrel1  = (const float*)d_in[3];
    const float* Wroot1 = (const float*)d_in[4];
    const float* b1     = (const float*)d_in[5];
    const float* Wrel2  = (const float*)d_in[6];
    const float* Wroot2 = (const float*)d_in[7];
    const float* b2     = (const float*)d_in[8];
    const float* Wrel3  = (const float*)d_in[9];
    const float* Wroot3 = (const float*)d_in[10];
    const float* b3     = (const float*)d_in[11];
    const float* Wlin   = (const float*)d_in[12];
    const float* blin   = (const float*)d_in[13];
    float* out = (float*)d_out;

    char* ws = (char*)d_ws;
    const size_t YB = (size_t)N_NODES * YSTR * sizeof(float);         // 6,400,000
    const size_t AB = (size_t)N_NODES * HID * sizeof(float);          // 4,000,000
    const size_t PB = (size_t)NBUCK * BCAP * sizeof(int);             // 8,388,608
    const size_t CB = (size_t)NBUCK * BCAP * sizeof(unsigned short);  // 4,194,304
    float*          yA     = (float*)(ws);
    float*          yB     = (float*)(ws + YB);
    float*          accA   = (float*)(ws + 2 * YB);
    float*          accB   = (float*)(ws + 2 * YB + AB);
    unsigned int*   padded = (unsigned int*)(ws + 2 * YB + 2 * AB);
    unsigned short* csr16  = (unsigned short*)(ws + 2 * YB + 2 * AB + PB);
    int*            startg = (int*)(ws + 2 * YB + 2 * AB + PB + CB);
    int*            cntg   = startg + N_NODES;
    unsigned short* permg  = (unsigned short*)(cntg + N_NODES);
    int*            gcur   = (int*)((char*)permg + (size_t)NBUCK * 256 * 2);
    int*            done   = gcur + NBUCK;
    float*          gmax   = (float*)(done + 4);
    float*          gsum   = gmax + N_GRAPHS * HID;
    float*          gcnt   = gsum + N_GRAPHS * HID;

    const int* src = ei;
    const int* dst = ei + N_EDGES;

    // zero bucket-fill counters + done flag (must be per-call)
    hipMemsetAsync(gcur, 0, (NBUCK + 1) * sizeof(int), stream);
    // K1: scatter (blocks 0-255) || layer-1 GEMM (+ pool init)
    k1_scatter_gemm<<<256 + GEMMB, 1024, 0, stream>>>(dst, src, gcur, padded,
                                                      x, Wrel1, Wroot1, b1, yA, accA,
                                                      gmax, gsum, gcnt);
    // K2: rank-trick counting sort + perm + L1 gather + L2 GEMM
    k2_build_gather<<<NBUCK, 1024, 0, stream>>>(gcur, padded, csr16, startg, cntg, permg,
                                                yA, accA, Wrel2, Wroot2, b2, yB, accB);
    // K3: L2 gather + L3 GEMM
    k3_gather_gemm<<<NBUCK, 1024, 0, stream>>>(startg, cntg, csr16, permg,
                                               yB, accB, Wrel3, Wroot3, b3, yA, accA);
    // K4: L3 gather + pooling + fused final linear (last block)
    k4_gather_pool<<<NBUCK, 1024, 0, stream>>>(startg, cntg, csr16, permg,
                                               yA, accA, batch, gmax, gsum, gcnt,
                                               done, Wlin, blin, out);
}

// Round 9
// 117.232 us; speedup vs baseline: 1.0436x; 1.0436x over previous
//
#include <hip/hip_runtime.h>

#define N_NODES  50000
#define N_EDGES  1600000
#define N_FEAT   50
#define HID      20
#define OUT_DIM  10
#define N_GRAPHS 64

#define NBUCK 196            // buckets: dst >> 8, 256 nodes each
#define BCAP  10240          // padded slots/bucket (avg 8163, ~23 sigma)
#define EPB   6250           // edges per scatter block (N_EDGES/256)
#define YSTR  32             // bf16 elements per y row -> 64 B, one cache line
#define GEMMB 977            // ceil(N_NODES*HID/1024)

__device__ __forceinline__ unsigned short f2bf(float f) {
    unsigned int u = __float_as_uint(f);
    u += 0x7FFFu + ((u >> 16) & 1u);          // round-to-nearest-even
    return (unsigned short)(u >> 16);
}
__device__ __forceinline__ unsigned int pk2(float f0, float f1) {
    return (unsigned int)f2bf(f0) | ((unsigned int)f2bf(f1) << 16);
}
__device__ __forceinline__ float blo(unsigned int u) { return __uint_as_float(u << 16); }
__device__ __forceinline__ float bhi(unsigned int u) { return __uint_as_float(u & 0xFFFF0000u); }

// add one bf16 message row (20 values, one 64B line) into 20 f32 registers
__device__ __forceinline__ void addrow(const unsigned short* __restrict__ yb,
                                       int sn, float* a) {
    const unsigned short* p = yb + (size_t)sn * YSTR;
    uint4 q0 = *(const uint4*)(p);        // values 0-7
    uint4 q1 = *(const uint4*)(p + 8);    // values 8-15
    uint2 q2 = *(const uint2*)(p + 16);   // values 16-19
    a[0] += blo(q0.x); a[1] += bhi(q0.x); a[2] += blo(q0.y); a[3] += bhi(q0.y);
    a[4] += blo(q0.z); a[5] += bhi(q0.z); a[6] += blo(q0.w); a[7] += bhi(q0.w);
    a[8] += blo(q1.x); a[9] += bhi(q1.x); a[10] += blo(q1.y); a[11] += bhi(q1.y);
    a[12] += blo(q1.z); a[13] += bhi(q1.z); a[14] += blo(q1.w); a[15] += bhi(q1.w);
    a[16] += blo(q2.x); a[17] += bhi(q2.x); a[18] += blo(q2.y); a[19] += bhi(q2.y);
}

// ================= K1: bucket scatter (rank trick + coalesced write) || gemm50 ======

__global__ __launch_bounds__(1024) void k1_scatter_gemm(
        const int* __restrict__ dst, const int* __restrict__ srcv,
        int* __restrict__ gcur, unsigned int* __restrict__ padded,
        const float* __restrict__ x, const float* __restrict__ Wrel,
        const float* __restrict__ Wroot, const float* __restrict__ bb,
        unsigned short* __restrict__ y, float* __restrict__ acc,
        float* __restrict__ gmax, float* __restrict__ gsum, float* __restrict__ gcnt) {
    __shared__ char smem[41728];
    int t = threadIdx.x;
    if (blockIdx.x < 256) {
        unsigned short* rnk = (unsigned short*)smem;           // 12500 B
        unsigned int*   ep2 = (unsigned int*)(smem + 12544);   // 25000 B
        int* cnt   = (int*)(smem + 37632);
        int* scn   = cnt + 256;
        int* lofs  = scn + 256;
        int* gbase = lofs + 256;
        if (blockIdx.x == 0) {
            for (int i = t; i < N_GRAPHS * HID; i += 1024) { gmax[i] = 0.f; gsum[i] = 0.f; }
            if (t < N_GRAPHS) gcnt[t] = 0.f;
        }
        if (t < 256) cnt[t] = 0;
        __syncthreads();
        int e0 = blockIdx.x * EPB;
        // pass 1: rank within bucket (1 LDS atomic/edge)
        for (int i = t; i < EPB; i += 1024) {
            int d = dst[e0 + i];
            rnk[i] = (unsigned short)atomicAdd(&cnt[d >> 8], 1);
        }
        __syncthreads();
        if (t < 256) scn[t] = cnt[t];
        __syncthreads();
        for (int d = 1; d < 256; d <<= 1) {
            int u = 0;
            if (t < 256 && t >= d) u = scn[t - d];
            __syncthreads();
            if (t < 256) scn[t] += u;
            __syncthreads();
        }
        if (t < 256) lofs[t] = scn[t] - cnt[t];
        if (t < NBUCK) gbase[t] = t * BCAP + atomicAdd(&gcur[t], cnt[t]);
        __syncthreads();
        // pass 2: re-read (L2-hot), place into bucket-grouped LDS (no atomic)
        for (int i = t; i < EPB; i += 1024) {
            unsigned int d = (unsigned int)dst[e0 + i];
            unsigned int s = (unsigned int)srcv[e0 + i];
            ep2[lofs[d >> 8] + rnk[i]] = (d << 16) | s;
        }
        __syncthreads();
        // pass 3: coalesced global write
        for (int i = t; i < EPB; i += 1024) {
            unsigned int e = ep2[i];
            int bk = e >> 24;
            int gp = gbase[bk] + (i - lofs[bk]);
            if (gp < (bk + 1) * BCAP) padded[gp] = e;  // guard never fires
        }
    } else {
        float* sWrel  = (float*)smem;
        float* sWroot = sWrel + N_FEAT * HID;
        for (int i = t; i < N_FEAT * HID; i += 1024) { sWrel[i] = Wrel[i]; sWroot[i] = Wroot[i]; }
        __syncthreads();
        int idx = (blockIdx.x - 256) * 1024 + t;
        if (idx < N_NODES * HID) {
            int n = idx / HID, j = idx % HID;
            const float* xr = x + n * N_FEAT;
            float a0 = 0.f, a1 = bb[j];
            #pragma unroll
            for (int k = 0; k < N_FEAT; ++k) {
                float xv = xr[k];
                a0 = fmaf(xv, sWrel[k * HID + j], a0);
                a1 = fmaf(xv, sWroot[k * HID + j], a1);
            }
            y[(size_t)n * YSTR + j] = f2bf(a0);
            acc[idx] = a1;
        }
    }
}

// ================= K2: counting sort + perm + gather1 (2 lanes/node) + gemm2 ========

__global__ __launch_bounds__(1024) void k2_build_gather(
        const int* __restrict__ gcur, const unsigned int* __restrict__ padded,
        unsigned short* __restrict__ csr16, int* __restrict__ startg,
        int* __restrict__ cntg, unsigned short* __restrict__ permg,
        const unsigned short* __restrict__ y_in, const float* __restrict__ accp,
        const float* __restrict__ Wrel, const float* __restrict__ Wroot,
        const float* __restrict__ bb,
        unsigned short* __restrict__ y_out, float* __restrict__ acc_out) {
    __shared__ unsigned short eo[BCAP];          // 20 KB sorted src lists
    __shared__ char uni[20480];                  // rnk (sort) then rh (gather)
    __shared__ float sWrel[HID * HID], sWroot[HID * HID], sb[HID];
    __shared__ int cnt[256], scn[256], s_start[256], s_cnt[256];
    __shared__ unsigned short sperm[256];
    unsigned short* rnk = (unsigned short*)uni;
    float*          rh  = (float*)uni;
    int g = blockIdx.x, t = threadIdx.x;
    int base = g * BCAP;
    int m = min(gcur[g], BCAP);
    int n0 = g * 256;
    int nvalid = min(256, N_NODES - n0);
    for (int i = t; i < HID * HID; i += 1024) { sWrel[i] = Wrel[i]; sWroot[i] = Wroot[i]; }
    if (t < HID) sb[t] = bb[t];
    if (t < 256) cnt[t] = 0;
    __syncthreads();
    // rank within node
    for (int i = t; i < m; i += 1024) {
        int local = (padded[base + i] >> 16) & 255;
        rnk[i] = (unsigned short)atomicAdd(&cnt[local], 1);
    }
    __syncthreads();
    if (t < 256) { s_cnt[t] = cnt[t]; scn[t] = cnt[t]; }
    __syncthreads();
    for (int d = 1; d < 256; d <<= 1) {
        int u = 0;
        if (t < 256 && t >= d) u = scn[t - d];
        __syncthreads();
        if (t < 256) scn[t] += u;
        __syncthreads();
    }
    if (t < 256) {
        s_start[t] = scn[t] - s_cnt[t];
        if (t < nvalid) { startg[n0 + t] = base + s_start[t]; cntg[n0 + t] = s_cnt[t]; }
    }
    __syncthreads();
    // place (no atomic)
    for (int i = t; i < m; i += 1024) {
        unsigned int e = padded[base + i];
        int local = (e >> 16) & 255;
        eo[s_start[local] + rnk[i]] = (unsigned short)(e & 0xFFFFu);
    }
    __syncthreads();                              // rnk dead after here
    for (int i = t; i < m; i += 1024) csr16[base + i] = eo[i];
    // degree-descending perm by comparison rank
    if (t < 256) {
        int d = s_cnt[t], rank = 0;
        for (int j2 = 0; j2 < 256; ++j2) {
            int dj = s_cnt[j2];
            rank += (dj > d) || (dj == d && j2 < t);
        }
        sperm[rank] = (unsigned short)t;
    }
    __syncthreads();
    if (t < 256) permg[g * 256 + t] = sperm[t];
    // gather: 2 lanes per node, register accumulation, eo from LDS
    bool act = t < 512;
    int slot = t >> 1, half = t & 1;
    float a[HID];
    #pragma unroll
    for (int j = 0; j < HID; ++j) a[j] = 0.f;
    int nl = 0; bool ok = false; int a0 = 0, cn = 0;
    if (act) {
        nl = sperm[slot];
        ok = nl < nvalid;
        if (ok) { a0 = s_start[nl]; cn = s_cnt[nl]; }
    }
    if (ok) {
        #pragma unroll 2
        for (int k = half; k < cn; k += 2) addrow(y_in, eo[a0 + k], a);
        if (half == 0) {
            const float4* ar = (const float4*)(accp + (size_t)(n0 + nl) * HID);
            #pragma unroll
            for (int q = 0; q < 5; ++q) {
                float4 v = ar[q];
                a[q*4+0] += v.x; a[q*4+1] += v.y; a[q*4+2] += v.z; a[q*4+3] += v.w;
            }
        }
    }
    if (ok && half == 0) {
        #pragma unroll
        for (int q = 0; q < 5; ++q)
            *(float4*)&rh[nl * HID + q * 4] =
                make_float4(a[q*4], a[q*4+1], a[q*4+2], a[q*4+3]);
    }
    __syncthreads();
    if (ok && half == 1) {
        #pragma unroll
        for (int q = 0; q < 5; ++q) {
            float4 v = *(float4*)&rh[nl * HID + q * 4];
            v.x += a[q*4]; v.y += a[q*4+1]; v.z += a[q*4+2]; v.w += a[q*4+3];
            *(float4*)&rh[nl * HID + q * 4] = v;
        }
    }
    __syncthreads();
    // gemm2 from LDS
    for (int i = t; i < nvalid * 5; i += 1024) {
        int n = i / 5, j0 = (i % 5) * 4;
        float y0 = 0.f, y1 = 0.f, y2 = 0.f, y3 = 0.f;
        float c0 = sb[j0], c1 = sb[j0+1], c2 = sb[j0+2], c3 = sb[j0+3];
        #pragma unroll
        for (int k = 0; k < HID; ++k) {
            float h = fmaxf(rh[n * HID + k], 0.f);
            const float* wr = sWrel  + k * HID + j0;
            const float* wo = sWroot + k * HID + j0;
            y0 = fmaf(h, wr[0], y0); y1 = fmaf(h, wr[1], y1);
            y2 = fmaf(h, wr[2], y2); y3 = fmaf(h, wr[3], y3);
            c0 = fmaf(h, wo[0], c0); c1 = fmaf(h, wo[1], c1);
            c2 = fmaf(h, wo[2], c2); c3 = fmaf(h, wo[3], c3);
        }
        *(uint2*)(y_out + (size_t)(n0 + n) * YSTR + j0) = make_uint2(pk2(y0, y1), pk2(y2, y3));
        *(float4*)(acc_out + (size_t)(n0 + n) * HID + j0) = make_float4(c0, c1, c2, c3);
    }
}

// ================= K3: gather (4 lanes/node, global csr) + gemm3 ====================

__global__ __launch_bounds__(1024) void k3_gather_gemm(
        const int* __restrict__ startg, const int* __restrict__ cntg,
        const unsigned short* __restrict__ csr16, const unsigned short* __restrict__ permg,
        const unsigned short* __restrict__ y_in, const float* __restrict__ accp,
        const float* __restrict__ Wrel, const float* __restrict__ Wroot,
        const float* __restrict__ bb,
        unsigned short* __restrict__ y_out, float* __restrict__ acc_out) {
    __shared__ float rh[256 * HID];
    __shared__ float rh2[256 * HID];
    __shared__ float sWrel[HID * HID], sWroot[HID * HID], sb[HID];
    __shared__ unsigned short sperm[256];
    int g = blockIdx.x, t = threadIdx.x;
    int n0 = g * 256;
    int nvalid = min(256, N_NODES - n0);
    for (int i = t; i < HID * HID; i += 1024) { sWrel[i] = Wrel[i]; sWroot[i] = Wroot[i]; }
    if (t < HID) sb[t] = bb[t];
    if (t < 256) sperm[t] = permg[g * 256 + t];
    __syncthreads();
    int slot = t >> 2, q = t & 3;
    int nl = sperm[slot];
    bool ok = nl < nvalid;
    float a[HID];
    #pragma unroll
    for (int j = 0; j < HID; ++j) a[j] = 0.f;
    if (ok) {
        int node = n0 + nl;
        int a0 = startg[node], cn = cntg[node];
        #pragma unroll 2
        for (int k = q; k < cn; k += 4) addrow(y_in, csr16[a0 + k], a);
        if (q == 0) {
            const float4* ar = (const float4*)(accp + (size_t)node * HID);
            #pragma unroll
            for (int qq = 0; qq < 5; ++qq) {
                float4 v = ar[qq];
                a[qq*4+0] += v.x; a[qq*4+1] += v.y; a[qq*4+2] += v.z; a[qq*4+3] += v.w;
            }
        }
    }
    if (ok && (q == 0 || q == 2)) {
        float* dstp = (q == 0) ? rh : rh2;
        #pragma unroll
        for (int qq = 0; qq < 5; ++qq)
            *(float4*)&dstp[nl * HID + qq * 4] =
                make_float4(a[qq*4], a[qq*4+1], a[qq*4+2], a[qq*4+3]);
    }
    __syncthreads();
    if (ok && (q == 1 || q == 3)) {
        float* dstp = (q == 1) ? rh : rh2;
        #pragma unroll
        for (int qq = 0; qq < 5; ++qq) {
            float4 v = *(float4*)&dstp[nl * HID + qq * 4];
            v.x += a[qq*4]; v.y += a[qq*4+1]; v.z += a[qq*4+2]; v.w += a[qq*4+3];
            *(float4*)&dstp[nl * HID + qq * 4] = v;
        }
    }
    __syncthreads();
    for (int i = t; i < nvalid * 5; i += 1024) {
        int n = i / 5, j0 = (i % 5) * 4;
        float y0 = 0.f, y1 = 0.f, y2 = 0.f, y3 = 0.f;
        float c0 = sb[j0], c1 = sb[j0+1], c2 = sb[j0+2], c3 = sb[j0+3];
        #pragma unroll
        for (int k = 0; k < HID; ++k) {
            float h = fmaxf(rh[n * HID + k] + rh2[n * HID + k], 0.f);
            const float* wr = sWrel  + k * HID + j0;
            const float* wo = sWroot + k * HID + j0;
            y0 = fmaf(h, wr[0], y0); y1 = fmaf(h, wr[1], y1);
            y2 = fmaf(h, wr[2], y2); y3 = fmaf(h, wr[3], y3);
            c0 = fmaf(h, wo[0], c0); c1 = fmaf(h, wo[1], c1);
            c2 = fmaf(h, wo[2], c2); c3 = fmaf(h, wo[3], c3);
        }
        *(uint2*)(y_out + (size_t)(n0 + n) * YSTR + j0) = make_uint2(pk2(y0, y1), pk2(y2, y3));
        *(float4*)(acc_out + (size_t)(n0 + n) * HID + j0) = make_float4(c0, c1, c2, c3);
    }
}

// ================= K4: gather (4 lanes/node) + pooling + last-block final linear ====

__global__ __launch_bounds__(1024) void k4_gather_pool(
        const int* __restrict__ startg, const int* __restrict__ cntg,
        const unsigned short* __restrict__ csr16, const unsigned short* __restrict__ permg,
        const unsigned short* __restrict__ y_in, const float* __restrict__ accp,
        const int* __restrict__ batch,
        float* __restrict__ gmax, float* __restrict__ gsum, float* __restrict__ gcnt,
        int* __restrict__ done, const float* __restrict__ Wlin,
        const float* __restrict__ blin, float* __restrict__ out) {
    __shared__ float rh[256 * HID];
    __shared__ float rh2[256 * HID];
    __shared__ float redm[51 * HID], reds[51 * HID];
    __shared__ unsigned short sperm[256];
    __shared__ int sbatch[256];
    __shared__ int seglo[16], seghi[16];
    __shared__ int lastFlag;
    int g = blockIdx.x, t = threadIdx.x;
    int n0 = g * 256;
    int nvalid = min(256, N_NODES - n0);
    if (t < 256) sperm[t] = permg[g * 256 + t];
    if (t < nvalid) sbatch[t] = batch[n0 + t];
    __syncthreads();
    int slot = t >> 2, q = t & 3;
    int nl = sperm[slot];
    bool ok = nl < nvalid;
    float a[HID];
    #pragma unroll
    for (int j = 0; j < HID; ++j) a[j] = 0.f;
    if (ok) {
        int node = n0 + nl;
        int a0 = startg[node], cn = cntg[node];
        #pragma unroll 2
        for (int k = q; k < cn; k += 4) addrow(y_in, csr16[a0 + k], a);
        if (q == 0) {
            const float4* ar = (const float4*)(accp + (size_t)node * HID);
            #pragma unroll
            for (int qq = 0; qq < 5; ++qq) {
                float4 v = ar[qq];
                a[qq*4+0] += v.x; a[qq*4+1] += v.y; a[qq*4+2] += v.z; a[qq*4+3] += v.w;
            }
        }
    }
    if (ok && (q == 0 || q == 2)) {
        float* dstp = (q == 0) ? rh : rh2;
        #pragma unroll
        for (int qq = 0; qq < 5; ++qq)
            *(float4*)&dstp[nl * HID + qq * 4] =
                make_float4(a[qq*4], a[qq*4+1], a[qq*4+2], a[qq*4+3]);
    }
    __syncthreads();
    if (ok && (q == 1 || q == 3)) {
        float* dstp = (q == 1) ? rh : rh2;
        #pragma unroll
        for (int qq = 0; qq < 5; ++qq) {
            float4 v = *(float4*)&dstp[nl * HID + qq * 4];
            v.x += a[qq*4]; v.y += a[qq*4+1]; v.z += a[qq*4+2]; v.w += a[qq*4+3];
            *(float4*)&dstp[nl * HID + qq * 4] = v;
        }
    }
    __syncthreads();
    // segmented max/mean pooling (batch sorted)
    int g0 = sbatch[0];
    int span = sbatch[nvalid - 1] - g0 + 1;
    if (t < nvalid) {
        int bi = sbatch[t] - g0;
        if (bi < 16) {
            if (t == 0 || sbatch[t - 1] != sbatch[t]) seglo[bi] = t;
            if (t == nvalid - 1 || sbatch[t + 1] != sbatch[t]) seghi[bi] = t + 1;
        }
    }
    __syncthreads();
    if (span > 16) span = 16;
    for (int li = 0; li < span; ++li) {
        int lo = seglo[li], hi = seghi[li];
        int r = t / HID, j = t % HID;
        if (r < 51) {
            float mx = 0.f, sm = 0.f;
            for (int n = lo + r; n < hi; n += 51) {
                float v = fmaxf(rh[n * HID + j] + rh2[n * HID + j], 0.f);
                mx = fmaxf(mx, v); sm += v;
            }
            redm[r * HID + j] = mx; reds[r * HID + j] = sm;
        }
        __syncthreads();
        if (t < HID) {
            float mm = 0.f, ss = 0.f;
            #pragma unroll 17
            for (int r2 = 0; r2 < 51; ++r2) {
                mm = fmaxf(mm, redm[r2 * HID + t]);
                ss += reds[r2 * HID + t];
            }
            atomicMax((int*)&gmax[(g0 + li) * HID + t], __float_as_int(mm));
            atomicAdd(&gsum[(g0 + li) * HID + t], ss);
        }
        if (t == HID) atomicAdd(&gcnt[g0 + li], (float)(hi - lo));
        __syncthreads();
    }
    // last block: final linear
    if (t == 0) {
        __threadfence();
        lastFlag = (atomicAdd(done, 1) == NBUCK - 1);
    }
    __syncthreads();
    if (!lastFlag) return;
    __threadfence();
    float* sW = redm;
    for (int i = t; i < 2 * HID * OUT_DIM; i += 1024) sW[i] = Wlin[i];
    __syncthreads();
    if (t < N_GRAPHS * OUT_DIM) {
        int gg = t / OUT_DIM, o = t % OUT_DIM;
        float c = fmaxf(gcnt[gg], 1.0f);
        float av = blin[o];
        #pragma unroll
        for (int j = 0; j < HID; ++j) {
            av = fmaf(gmax[gg * HID + j], sW[j * OUT_DIM + o], av);
            av = fmaf(gsum[gg * HID + j] / c, sW[(HID + j) * OUT_DIM + o], av);
        }
        out[t] = av;
    }
}

extern "C" void kernel_launch(void* const* d_in, const int* in_sizes, int n_in,
                              void* d_out, int out_size, void* d_ws, size_t ws_size,
                              hipStream_t stream) {
    const float* x      = (const float*)d_in[0];
    const int*   ei     = (const int*)  d_in[1];
    const int*   batch  = (const int*)  d_in[2];
    const float* Wrel1  = (const float*)d_in[3];
    const float* Wroot1 = (const float*)d_in[4];
    const float* b1     = (const float*)d_in[5];
    const float* Wrel2  = (const float*)d_in[6];
    const float* Wroot2 = (const float*)d_in[7];
    const float* b2     = (const float*)d_in[8];
    const float* Wrel3  = (const float*)d_in[9];
    const float* Wroot3 = (const float*)d_in[10];
    const float* b3     = (const float*)d_in[11];
    const float* Wlin   = (const float*)d_in[12];
    const float* blin   = (const float*)d_in[13];
    float* out = (float*)d_out;

    char* ws = (char*)d_ws;
    const size_t YB = (size_t)N_NODES * YSTR * 2;                   // 3,200,000 (bf16)
    const size_t AB = (size_t)N_NODES * HID * 4;                    // 4,000,000
    const size_t PB = (size_t)NBUCK * BCAP * 4;                     // 8,028,160
    const size_t CB = (size_t)NBUCK * BCAP * 2;                     // 4,014,080
    const size_t NP = (size_t)NBUCK * 256;                          // 50,176
    unsigned short* yA     = (unsigned short*)(ws);
    unsigned short* yB     = (unsigned short*)(ws + YB);
    float*          accA   = (float*)(ws + 2 * YB);
    float*          accB   = (float*)(ws + 2 * YB + AB);
    unsigned int*   padded = (unsigned int*)(ws + 2 * YB + 2 * AB);
    unsigned short* csr16  = (unsigned short*)(ws + 2 * YB + 2 * AB + PB);
    int*            startg = (int*)(ws + 2 * YB + 2 * AB + PB + CB);
    int*            cntg   = startg + NP;
    unsigned short* permg  = (unsigned short*)(cntg + NP);
    int*            gcur   = (int*)((char*)permg + NP * 2);
    int*            done   = gcur + NBUCK;
    float*          gmax   = (float*)(done + 4);
    float*          gsum   = gmax + N_GRAPHS * HID;
    float*          gcnt   = gsum + N_GRAPHS * HID;

    const int* src = ei;
    const int* dst = ei + N_EDGES;

    hipMemsetAsync(gcur, 0, (NBUCK + 1) * sizeof(int), stream);
    // K1: scatter (blocks 0-255, rank-trick + coalesced write) || gemm50 -> bf16 y
    k1_scatter_gemm<<<256 + GEMMB, 1024, 0, stream>>>(dst, src, gcur, padded,
                                                      x, Wrel1, Wroot1, b1, yA, accA,
                                                      gmax, gsum, gcnt);
    // K2: counting sort + perm + L1 gather (2 lanes/node, LDS src) + gemm2
    k2_build_gather<<<NBUCK, 1024, 0, stream>>>(gcur, padded, csr16, startg, cntg, permg,
                                                yA, accA, Wrel2, Wroot2, b2, yB, accB);
    // K3: L2 gather (4 lanes/node) + gemm3
    k3_gather_gemm<<<NBUCK, 1024, 0, stream>>>(startg, cntg, csr16, permg,
                                               yB, accB, Wrel3, Wroot3, b3, yA, accA);
    // K4: L3 gather + pooling + fused final linear
    k4_gather_pool<<<NBUCK, 1024, 0, stream>>>(startg, cntg, csr16, permg,
                                               yA, accA, batch, gmax, gsum, gcnt,
                                               done, Wlin, blin, out);
}